// Round 1
// baseline (4288.299 us; speedup 1.0000x reference)
//
#include <hip/hip_runtime.h>

#define N_NODES 50000
#define N_EDGES 800000
#define IN_DIM  128
#define HID_DIM 256
#define OUT_DIM 128

// ---------------- degree ----------------

__global__ void zero_int_kernel(int* __restrict__ p, int n) {
    int i = blockIdx.x * blockDim.x + threadIdx.x;
    if (i < n) p[i] = 0;
}

__global__ void count_deg_kernel(const int* __restrict__ dst, int* __restrict__ cnt) {
    int e = blockIdx.x * blockDim.x + threadIdx.x;
    if (e < N_EDGES) atomicAdd(&cnt[dst[e]], 1);
}

__global__ void dinv_kernel(const int* __restrict__ cnt, float* __restrict__ dinv) {
    int i = blockIdx.x * blockDim.x + threadIdx.x;
    if (i < N_NODES) dinv[i] = rsqrtf((float)cnt[i] + 1.0f);
}

// ---------------- GEMM1: h1 = x @ W1   [N,128]x[128,256] ----------------
// 8 rows per block, 256 threads (one output column each).

__global__ __launch_bounds__(256) void gemm1_kernel(const float* __restrict__ x,
                                                    const float* __restrict__ W1,
                                                    float* __restrict__ h1) {
    __shared__ float xs[8][IN_DIM];
    const int row0 = blockIdx.x * 8;
    for (int t = threadIdx.x; t < 8 * IN_DIM; t += 256) {
        int r = t >> 7, k = t & 127;
        xs[r][k] = x[(row0 + r) * IN_DIM + k];
    }
    __syncthreads();
    const int j = threadIdx.x;
    float acc[8] = {0.f, 0.f, 0.f, 0.f, 0.f, 0.f, 0.f, 0.f};
    for (int k = 0; k < IN_DIM; ++k) {
        float w = W1[k * HID_DIM + j];
#pragma unroll
        for (int r = 0; r < 8; ++r) acc[r] += xs[r][k] * w;
    }
#pragma unroll
    for (int r = 0; r < 8; ++r) h1[(row0 + r) * HID_DIM + j] = acc[r];
}

// ---------------- self-loop init: agg = h * dinv^2 ----------------

__global__ void init_self1_kernel(const float* __restrict__ h1,
                                  const float* __restrict__ dinv,
                                  float* __restrict__ agg) {
    int idx = blockIdx.x * blockDim.x + threadIdx.x;  // N*256 total
    int i = idx >> 8;
    float d = dinv[i];
    agg[idx] = h1[idx] * d * d;
}

// ---------------- scatter layer 1: one wave (64 lanes) per edge ----------------

__global__ __launch_bounds__(256) void scatter1_kernel(const int* __restrict__ src,
                                                       const int* __restrict__ dst,
                                                       const float* __restrict__ dinv,
                                                       const float* __restrict__ h1,
                                                       float* __restrict__ agg) {
    int e = blockIdx.x * 4 + (threadIdx.x >> 6);
    int lane = threadIdx.x & 63;
    int s = src[e], d = dst[e];
    float norm = dinv[s] * dinv[d];
    float4 v = ((const float4*)(h1 + s * HID_DIM))[lane];
    float* ap = agg + d * HID_DIM + lane * 4;
    atomicAdd(ap + 0, v.x * norm);
    atomicAdd(ap + 1, v.y * norm);
    atomicAdd(ap + 2, v.z * norm);
    atomicAdd(ap + 3, v.w * norm);
}

// ---------------- GEMM2: h2 = relu(agg1 + b1) @ W2   [N,256]x[256,128] ----------------
// relu + bias fused into the LDS staging read. 8 rows/block, 128 threads.

__global__ __launch_bounds__(128) void gemm2_kernel(const float* __restrict__ agg,
                                                    const float* __restrict__ b1,
                                                    const float* __restrict__ W2,
                                                    float* __restrict__ h2) {
    __shared__ float as[8][HID_DIM];
    const int row0 = blockIdx.x * 8;
    for (int t = threadIdx.x; t < 8 * HID_DIM; t += 128) {
        int r = t >> 8, k = t & 255;
        float v = agg[(row0 + r) * HID_DIM + k] + b1[k];
        as[r][k] = v > 0.f ? v : 0.f;
    }
    __syncthreads();
    const int j = threadIdx.x;
    float acc[8] = {0.f, 0.f, 0.f, 0.f, 0.f, 0.f, 0.f, 0.f};
    for (int k = 0; k < HID_DIM; ++k) {
        float w = W2[k * OUT_DIM + j];
#pragma unroll
        for (int r = 0; r < 8; ++r) acc[r] += as[r][k] * w;
    }
#pragma unroll
    for (int r = 0; r < 8; ++r) h2[(row0 + r) * OUT_DIM + j] = acc[r];
}

// ---------------- self-loop init layer2 (writes every d_out element) ----------------

__global__ void init_self2_kernel(const float* __restrict__ h2,
                                  const float* __restrict__ dinv,
                                  float* __restrict__ out) {
    int idx = blockIdx.x * blockDim.x + threadIdx.x;  // N*128 total
    int i = idx >> 7;
    float d = dinv[i];
    out[idx] = h2[idx] * d * d;
}

// ---------------- scatter layer 2: half-wave (32 lanes) per edge ----------------

__global__ __launch_bounds__(256) void scatter2_kernel(const int* __restrict__ src,
                                                       const int* __restrict__ dst,
                                                       const float* __restrict__ dinv,
                                                       const float* __restrict__ h2,
                                                       float* __restrict__ out) {
    int e = blockIdx.x * 8 + (threadIdx.x >> 5);
    int lane = threadIdx.x & 31;
    int s = src[e], d = dst[e];
    float norm = dinv[s] * dinv[d];
    float4 v = ((const float4*)(h2 + s * OUT_DIM))[lane];
    float* op = out + d * OUT_DIM + lane * 4;
    atomicAdd(op + 0, v.x * norm);
    atomicAdd(op + 1, v.y * norm);
    atomicAdd(op + 2, v.z * norm);
    atomicAdd(op + 3, v.w * norm);
}

// ---------------- final bias ----------------

__global__ void bias2_kernel(float* __restrict__ out, const float* __restrict__ b2) {
    int idx = blockIdx.x * blockDim.x + threadIdx.x;  // N*128 total
    out[idx] += b2[idx & 127];
}

extern "C" void kernel_launch(void* const* d_in, const int* in_sizes, int n_in,
                              void* d_out, int out_size, void* d_ws, size_t ws_size,
                              hipStream_t stream) {
    const float* x  = (const float*)d_in[0];
    const int*   ei = (const int*)d_in[1];
    const float* W1 = (const float*)d_in[2];
    const float* b1 = (const float*)d_in[3];
    const float* W2 = (const float*)d_in[4];
    const float* b2 = (const float*)d_in[5];
    float* out = (float*)d_out;

    const int* src = ei;             // edge_index[0]
    const int* dst = ei + N_EDGES;   // edge_index[1]

    // workspace layout (bytes):
    //  cnt  : [0, 200000)               int[50000]
    //  dinv : [200000, 400000)          float[50000]
    //  h1   : [400000, 51600000)        float[50000*256]
    //  agg1 : [51600000, 102800000)     float[50000*256]
    //  h2   : [102800000, 128400000)    float[50000*128]
    char* ws = (char*)d_ws;
    int*   cnt  = (int*)(ws);
    float* dinv = (float*)(ws + 200000);
    float* h1   = (float*)(ws + 400000);
    float* agg1 = (float*)(ws + 51600000);
    float* h2   = (float*)(ws + 102800000);

    // degree
    zero_int_kernel<<<(N_NODES + 255) / 256, 256, 0, stream>>>(cnt, N_NODES);
    count_deg_kernel<<<N_EDGES / 256, 256, 0, stream>>>(dst, cnt);
    dinv_kernel<<<(N_NODES + 255) / 256, 256, 0, stream>>>(cnt, dinv);

    // layer 1
    gemm1_kernel<<<N_NODES / 8, 256, 0, stream>>>(x, W1, h1);
    init_self1_kernel<<<(N_NODES * HID_DIM) / 256, 256, 0, stream>>>(h1, dinv, agg1);
    scatter1_kernel<<<N_EDGES / 4, 256, 0, stream>>>(src, dst, dinv, h1, agg1);

    // layer 2 (relu + b1 fused into gemm2 staging)
    gemm2_kernel<<<N_NODES / 8, 128, 0, stream>>>(agg1, b1, W2, h2);
    init_self2_kernel<<<(N_NODES * OUT_DIM) / 256, 256, 0, stream>>>(h2, dinv, out);
    scatter2_kernel<<<N_EDGES / 8, 256, 0, stream>>>(src, dst, dinv, h2, out);
    bias2_kernel<<<(N_NODES * OUT_DIM) / 256, 256, 0, stream>>>(out, b2);
}

// Round 2
// 455.353 us; speedup vs baseline: 9.4175x; 9.4175x over previous
//
#include <hip/hip_runtime.h>

#define N_NODES 50000
#define N_EDGES 800000
#define IN_DIM  128
#define HID_DIM 256
#define OUT_DIM 128
#define BUCKET_CAP 64   // in-degree ~ Poisson(16); P(deg>64) ~ 2e-18 over 50k nodes

__device__ inline void fma4(float4& a, const float4 v, float n) {
    a.x += v.x * n; a.y += v.y * n; a.z += v.z * n; a.w += v.w * n;
}
__device__ inline void fma2(float2& a, const float2 v, float n) {
    a.x += v.x * n; a.y += v.y * n;
}

// ---------------- degree + bucket build ----------------

__global__ void zero_int_kernel(int* __restrict__ p, int n) {
    int i = blockIdx.x * blockDim.x + threadIdx.x;
    if (i < n) p[i] = 0;
}

// pos = cnt[d]++; bucket[d*64+pos] = s   (int atomics only, ~800k)
__global__ void fill_bucket_kernel(const int* __restrict__ src, const int* __restrict__ dst,
                                   int* __restrict__ cnt, int* __restrict__ bucket) {
    int e = blockIdx.x * blockDim.x + threadIdx.x;
    if (e >= N_EDGES) return;
    int d = dst[e];
    int pos = atomicAdd(&cnt[d], 1);
    bucket[d * BUCKET_CAP + pos] = src[e];
}

__global__ void dinv_kernel(const int* __restrict__ cnt, float* __restrict__ dinv) {
    int i = blockIdx.x * blockDim.x + threadIdx.x;
    if (i < N_NODES) dinv[i] = rsqrtf((float)cnt[i] + 1.0f);
}

// ---------------- GEMM1: h1 = x @ W1   [N,128]x[128,256] ----------------

__global__ __launch_bounds__(256) void gemm1_kernel(const float* __restrict__ x,
                                                    const float* __restrict__ W1,
                                                    float* __restrict__ h1) {
    __shared__ float xs[8][IN_DIM];
    const int row0 = blockIdx.x * 8;
    for (int t = threadIdx.x; t < 8 * IN_DIM; t += 256) {
        int r = t >> 7, k = t & 127;
        xs[r][k] = x[(row0 + r) * IN_DIM + k];
    }
    __syncthreads();
    const int j = threadIdx.x;
    float acc[8] = {0.f, 0.f, 0.f, 0.f, 0.f, 0.f, 0.f, 0.f};
    for (int k = 0; k < IN_DIM; ++k) {
        float w = W1[k * HID_DIM + j];
#pragma unroll
        for (int r = 0; r < 8; ++r) acc[r] += xs[r][k] * w;
    }
#pragma unroll
    for (int r = 0; r < 8; ++r) h1[(row0 + r) * HID_DIM + j] = acc[r];
}

// ---------------- gather layer 1: one wave per dst node, no atomics ----------------
// agg[d] = h1[d]*dinv_d^2 + sum_{s in bucket[d]} h1[s] * dinv_s * dinv_d

__global__ __launch_bounds__(256) void gather1_kernel(const int* __restrict__ cnt,
                                                      const int* __restrict__ bucket,
                                                      const float* __restrict__ dinv,
                                                      const float* __restrict__ h1,
                                                      float* __restrict__ agg) {
    const int w = blockIdx.x * 4 + (threadIdx.x >> 6);   // dst node, one wave each
    const int lane = threadIdx.x & 63;
    const int n = cnt[w];
    const float dd = dinv[w];
    // preload this wave's src ids + per-edge norms, one per lane
    int   sv = (lane < n) ? bucket[w * BUCKET_CAP + lane] : 0;
    float nv = (lane < n) ? dinv[sv] * dd : 0.f;

    // self-loop term
    float4 a = ((const float4*)(h1 + (size_t)w * HID_DIM))[lane];
    float sd = dd * dd;
    float4 acc0 = {a.x * sd, a.y * sd, a.z * sd, a.w * sd};
    float4 acc1 = {0.f, 0.f, 0.f, 0.f};
    float4 acc2 = {0.f, 0.f, 0.f, 0.f};
    float4 acc3 = {0.f, 0.f, 0.f, 0.f};

    int i = 0;
    for (; i + 3 < n; i += 4) {
        int s0 = __shfl(sv, i), s1 = __shfl(sv, i + 1), s2 = __shfl(sv, i + 2), s3 = __shfl(sv, i + 3);
        float n0 = __shfl(nv, i), n1 = __shfl(nv, i + 1), n2 = __shfl(nv, i + 2), n3 = __shfl(nv, i + 3);
        float4 v0 = ((const float4*)(h1 + (size_t)s0 * HID_DIM))[lane];
        float4 v1 = ((const float4*)(h1 + (size_t)s1 * HID_DIM))[lane];
        float4 v2 = ((const float4*)(h1 + (size_t)s2 * HID_DIM))[lane];
        float4 v3 = ((const float4*)(h1 + (size_t)s3 * HID_DIM))[lane];
        fma4(acc0, v0, n0); fma4(acc1, v1, n1); fma4(acc2, v2, n2); fma4(acc3, v3, n3);
    }
    for (; i < n; ++i) {
        int s = __shfl(sv, i);
        float nm = __shfl(nv, i);
        float4 v = ((const float4*)(h1 + (size_t)s * HID_DIM))[lane];
        fma4(acc0, v, nm);
    }
    acc0.x += acc1.x + acc2.x + acc3.x;
    acc0.y += acc1.y + acc2.y + acc3.y;
    acc0.z += acc1.z + acc2.z + acc3.z;
    acc0.w += acc1.w + acc2.w + acc3.w;
    ((float4*)(agg + (size_t)w * HID_DIM))[lane] = acc0;
}

// ---------------- GEMM2: h2 = relu(agg1 + b1) @ W2   [N,256]x[256,128] ----------------

__global__ __launch_bounds__(128) void gemm2_kernel(const float* __restrict__ agg,
                                                    const float* __restrict__ b1,
                                                    const float* __restrict__ W2,
                                                    float* __restrict__ h2) {
    __shared__ float as[8][HID_DIM];
    const int row0 = blockIdx.x * 8;
    for (int t = threadIdx.x; t < 8 * HID_DIM; t += 128) {
        int r = t >> 8, k = t & 255;
        float v = agg[(row0 + r) * HID_DIM + k] + b1[k];
        as[r][k] = v > 0.f ? v : 0.f;
    }
    __syncthreads();
    const int j = threadIdx.x;
    float acc[8] = {0.f, 0.f, 0.f, 0.f, 0.f, 0.f, 0.f, 0.f};
    for (int k = 0; k < HID_DIM; ++k) {
        float w = W2[k * OUT_DIM + j];
#pragma unroll
        for (int r = 0; r < 8; ++r) acc[r] += as[r][k] * w;
    }
#pragma unroll
    for (int r = 0; r < 8; ++r) h2[(row0 + r) * OUT_DIM + j] = acc[r];
}

// ---------------- gather layer 2: one wave per dst node, fused self + b2 ----------------
// out[d] = h2[d]*dinv_d^2 + sum h2[s]*norm + b2

__global__ __launch_bounds__(256) void gather2_kernel(const int* __restrict__ cnt,
                                                      const int* __restrict__ bucket,
                                                      const float* __restrict__ dinv,
                                                      const float* __restrict__ h2,
                                                      const float* __restrict__ b2,
                                                      float* __restrict__ out) {
    const int w = blockIdx.x * 4 + (threadIdx.x >> 6);
    const int lane = threadIdx.x & 63;
    const int n = cnt[w];
    const float dd = dinv[w];
    int   sv = (lane < n) ? bucket[w * BUCKET_CAP + lane] : 0;
    float nv = (lane < n) ? dinv[sv] * dd : 0.f;

    float2 bb = ((const float2*)b2)[lane];
    float2 a = ((const float2*)(h2 + (size_t)w * OUT_DIM))[lane];
    float sd = dd * dd;
    float2 acc0 = {a.x * sd + bb.x, a.y * sd + bb.y};
    float2 acc1 = {0.f, 0.f};
    float2 acc2 = {0.f, 0.f};
    float2 acc3 = {0.f, 0.f};

    int i = 0;
    for (; i + 3 < n; i += 4) {
        int s0 = __shfl(sv, i), s1 = __shfl(sv, i + 1), s2 = __shfl(sv, i + 2), s3 = __shfl(sv, i + 3);
        float n0 = __shfl(nv, i), n1 = __shfl(nv, i + 1), n2 = __shfl(nv, i + 2), n3 = __shfl(nv, i + 3);
        float2 v0 = ((const float2*)(h2 + (size_t)s0 * OUT_DIM))[lane];
        float2 v1 = ((const float2*)(h2 + (size_t)s1 * OUT_DIM))[lane];
        float2 v2 = ((const float2*)(h2 + (size_t)s2 * OUT_DIM))[lane];
        float2 v3 = ((const float2*)(h2 + (size_t)s3 * OUT_DIM))[lane];
        fma2(acc0, v0, n0); fma2(acc1, v1, n1); fma2(acc2, v2, n2); fma2(acc3, v3, n3);
    }
    for (; i < n; ++i) {
        int s = __shfl(sv, i);
        float nm = __shfl(nv, i);
        float2 v = ((const float2*)(h2 + (size_t)s * OUT_DIM))[lane];
        fma2(acc0, v, nm);
    }
    acc0.x += acc1.x + acc2.x + acc3.x;
    acc0.y += acc1.y + acc2.y + acc3.y;
    ((float2*)(out + (size_t)w * OUT_DIM))[lane] = acc0;
}

extern "C" void kernel_launch(void* const* d_in, const int* in_sizes, int n_in,
                              void* d_out, int out_size, void* d_ws, size_t ws_size,
                              hipStream_t stream) {
    const float* x  = (const float*)d_in[0];
    const int*   ei = (const int*)d_in[1];
    const float* W1 = (const float*)d_in[2];
    const float* b1 = (const float*)d_in[3];
    const float* W2 = (const float*)d_in[4];
    const float* b2 = (const float*)d_in[5];
    float* out = (float*)d_out;

    const int* src = ei;             // edge_index[0]
    const int* dst = ei + N_EDGES;   // edge_index[1]

    // workspace layout (bytes):
    //  cnt    : [0, 200000)                  int[50000]
    //  dinv   : [200000, 400000)             float[50000]
    //  bucket : [400000, 13200000)           int[50000*64]
    //  h1/h2  : [13200000, 64400000)         float[50000*256]  (h2 aliases h1 after gather1)
    //  agg1   : [64400000, 115600000)        float[50000*256]
    char* ws = (char*)d_ws;
    int*   cnt    = (int*)(ws);
    float* dinv   = (float*)(ws + 200000);
    int*   bucket = (int*)(ws + 400000);
    float* h1     = (float*)(ws + 13200000);
    float* h2     = (float*)(ws + 13200000);   // alias: h1 dead after gather1
    float* agg1   = (float*)(ws + 64400000);

    // graph build (int atomics only)
    zero_int_kernel<<<(N_NODES + 255) / 256, 256, 0, stream>>>(cnt, N_NODES);
    fill_bucket_kernel<<<N_EDGES / 256, 256, 0, stream>>>(src, dst, cnt, bucket);
    dinv_kernel<<<(N_NODES + 255) / 256, 256, 0, stream>>>(cnt, dinv);

    // layer 1
    gemm1_kernel<<<N_NODES / 8, 256, 0, stream>>>(x, W1, h1);
    gather1_kernel<<<N_NODES / 4, 256, 0, stream>>>(cnt, bucket, dinv, h1, agg1);

    // layer 2 (relu + b1 fused into gemm2 staging; self-loop + b2 fused into gather2)
    gemm2_kernel<<<N_NODES / 8, 128, 0, stream>>>(agg1, b1, W2, h2);
    gather2_kernel<<<N_NODES / 4, 256, 0, stream>>>(cnt, bucket, dinv, h2, b2, out);
}

// Round 3
// 282.562 us; speedup vs baseline: 15.1765x; 1.6115x over previous
//
#include <hip/hip_runtime.h>

#define N_NODES 50000
#define N_EDGES 800000
#define IN_DIM  128
#define HID_DIM 256
#define OUT_DIM 128
#define BUCKET_CAP 64   // in-degree ~ Poisson(16); P(deg>64) ~ 2e-18 over 50k nodes

typedef __attribute__((ext_vector_type(8))) short short8;
typedef __attribute__((ext_vector_type(4))) float f32x4;

// ---- bf16 helpers (RNE) ----
__device__ inline ushort f2b(float f) {
    union { float f; unsigned u; } v; v.f = f;
    return (ushort)((v.u + 0x7FFFu + ((v.u >> 16) & 1u)) >> 16);
}
__device__ inline float b2f(ushort h) {
    union { unsigned u; float f; } v; v.u = ((unsigned)h) << 16;
    return v.f;
}
__device__ inline float2 u2f2(unsigned u) {
    float2 r; r.x = b2f((ushort)(u & 0xFFFFu)); r.y = b2f((ushort)(u >> 16)); return r;
}
__device__ inline void fma2(float2& a, const float2 v, float n) {
    a.x += v.x * n; a.y += v.y * n;
}

// ---------------- graph build ----------------

__global__ void zero_int_kernel(int* __restrict__ p, int n) {
    int i = blockIdx.x * blockDim.x + threadIdx.x;
    if (i < n) p[i] = 0;
}

__global__ void fill_bucket_kernel(const int* __restrict__ src, const int* __restrict__ dst,
                                   int* __restrict__ cnt, int* __restrict__ bucket) {
    int e = blockIdx.x * blockDim.x + threadIdx.x;
    if (e >= N_EDGES) return;
    int d = dst[e];
    int pos = atomicAdd(&cnt[d], 1);
    bucket[d * BUCKET_CAP + pos] = src[e];
}

__global__ void dinv_kernel(const int* __restrict__ cnt, float* __restrict__ dinv) {
    int i = blockIdx.x * blockDim.x + threadIdx.x;
    if (i < N_NODES) dinv[i] = rsqrtf((float)cnt[i] + 1.0f);
}

// ---------------- fp32 -> bf16 conversions ----------------

__global__ void conv_x_kernel(const float* __restrict__ x, ushort* __restrict__ xb) {
    int i = blockIdx.x * blockDim.x + threadIdx.x;  // over 6.4M/4
    float4 v = ((const float4*)x)[i];
    ushort4 o; o.x = f2b(v.x); o.y = f2b(v.y); o.z = f2b(v.z); o.w = f2b(v.w);
    ((ushort4*)xb)[i] = o;
}

// W1 [128x256] -> w1t [256x128] (bf16, transposed); W2 [256x128] -> w2t [128x256]
__global__ void conv_w_kernel(const float* __restrict__ W1, const float* __restrict__ W2,
                              ushort* __restrict__ w1t, ushort* __restrict__ w2t) {
    int i = blockIdx.x * blockDim.x + threadIdx.x;  // 65536 total
    if (i < 32768) {
        int n = i >> 7, k = i & 127;
        w1t[i] = f2b(W1[k * HID_DIM + n]);
    } else {
        int j = i - 32768;
        int n = j >> 8, k = j & 255;
        w2t[j] = f2b(W2[k * OUT_DIM + n]);
    }
}

// ---------------- gather0: aggx = Ahat * x  (bf16 in/out, fp32 acc) ----------------
// one wave per dst node; lane covers 2 features (features 2*lane, 2*lane+1)

__global__ __launch_bounds__(256) void gather0_kernel(const int* __restrict__ cnt,
                                                      const int* __restrict__ bucket,
                                                      const float* __restrict__ dinv,
                                                      const ushort* __restrict__ xb,
                                                      ushort* __restrict__ aggxb) {
    const int w = blockIdx.x * 4 + (threadIdx.x >> 6);
    const int lane = threadIdx.x & 63;
    const int n = cnt[w];
    const float dd = dinv[w];
    int   sv = (lane < n) ? bucket[w * BUCKET_CAP + lane] : 0;
    float nv = (lane < n) ? dinv[sv] * dd : 0.f;

    float2 self = u2f2(((const unsigned*)(xb + (size_t)w * IN_DIM))[lane]);
    float sd = dd * dd;
    float2 acc0 = {self.x * sd, self.y * sd};
    float2 acc1 = {0.f, 0.f}, acc2 = {0.f, 0.f}, acc3 = {0.f, 0.f};

    int i = 0;
    for (; i + 3 < n; i += 4) {
        int s0 = __shfl(sv, i), s1 = __shfl(sv, i + 1), s2 = __shfl(sv, i + 2), s3 = __shfl(sv, i + 3);
        float n0 = __shfl(nv, i), n1 = __shfl(nv, i + 1), n2 = __shfl(nv, i + 2), n3 = __shfl(nv, i + 3);
        unsigned u0 = ((const unsigned*)(xb + (size_t)s0 * IN_DIM))[lane];
        unsigned u1 = ((const unsigned*)(xb + (size_t)s1 * IN_DIM))[lane];
        unsigned u2 = ((const unsigned*)(xb + (size_t)s2 * IN_DIM))[lane];
        unsigned u3 = ((const unsigned*)(xb + (size_t)s3 * IN_DIM))[lane];
        fma2(acc0, u2f2(u0), n0); fma2(acc1, u2f2(u1), n1);
        fma2(acc2, u2f2(u2), n2); fma2(acc3, u2f2(u3), n3);
    }
    for (; i < n; ++i) {
        int s = __shfl(sv, i);
        float nm = __shfl(nv, i);
        fma2(acc0, u2f2(((const unsigned*)(xb + (size_t)s * IN_DIM))[lane]), nm);
    }
    acc0.x += acc1.x + acc2.x + acc3.x;
    acc0.y += acc1.y + acc2.y + acc3.y;
    unsigned o = (unsigned)f2b(acc0.x) | ((unsigned)f2b(acc0.y) << 16);
    ((unsigned*)(aggxb + (size_t)w * IN_DIM))[lane] = o;
}

// ---------------- gemm1 (MFMA): Hb = relu(aggx @ W1 + b1), bf16 out ----------------
// grid 3125 blocks x 256 thr; block = 16 rows; wave w covers cols [64w, 64w+64)

__global__ __launch_bounds__(256) void gemm1_mfma(const ushort* __restrict__ aggxb,
                                                  const ushort* __restrict__ w1t,
                                                  const float* __restrict__ b1,
                                                  ushort* __restrict__ Hb) {
    const int row0 = blockIdx.x * 16;
    const int wv = threadIdx.x >> 6;
    const int lane = threadIdx.x & 63;
    const int l15 = lane & 15, q = lane >> 4;
    f32x4 acc[4] = {{0.f, 0.f, 0.f, 0.f}, {0.f, 0.f, 0.f, 0.f},
                    {0.f, 0.f, 0.f, 0.f}, {0.f, 0.f, 0.f, 0.f}};
    const ushort* abase = aggxb + (size_t)(row0 + l15) * IN_DIM + q * 8;
#pragma unroll
    for (int kb = 0; kb < 4; ++kb) {
        short8 a = *(const short8*)(abase + kb * 32);
#pragma unroll
        for (int t = 0; t < 4; ++t) {
            int col = wv * 64 + t * 16 + l15;
            short8 b = *(const short8*)(w1t + (size_t)col * IN_DIM + kb * 32 + q * 8);
            acc[t] = __builtin_amdgcn_mfma_f32_16x16x32_bf16(a, b, acc[t], 0, 0, 0);
        }
    }
#pragma unroll
    for (int t = 0; t < 4; ++t) {
        int col = wv * 64 + t * 16 + l15;
        float bias = b1[col];
#pragma unroll
        for (int r = 0; r < 4; ++r) {
            int row = row0 + q * 4 + r;
            float v = acc[t][r] + bias;
            Hb[(size_t)row * HID_DIM + col] = f2b(v > 0.f ? v : 0.f);
        }
    }
}

// ---------------- gemm2 (MFMA): h2b = Hb @ W2, bf16 out ----------------
// grid 3125 blocks x 256 thr; block = 16 rows; wave w covers cols [32w, 32w+32)

__global__ __launch_bounds__(256) void gemm2_mfma(const ushort* __restrict__ Hb,
                                                  const ushort* __restrict__ w2t,
                                                  ushort* __restrict__ h2b) {
    const int row0 = blockIdx.x * 16;
    const int wv = threadIdx.x >> 6;
    const int lane = threadIdx.x & 63;
    const int l15 = lane & 15, q = lane >> 4;
    f32x4 acc[2] = {{0.f, 0.f, 0.f, 0.f}, {0.f, 0.f, 0.f, 0.f}};
    const ushort* abase = Hb + (size_t)(row0 + l15) * HID_DIM + q * 8;
#pragma unroll
    for (int kb = 0; kb < 8; ++kb) {
        short8 a = *(const short8*)(abase + kb * 32);
#pragma unroll
        for (int t = 0; t < 2; ++t) {
            int col = wv * 32 + t * 16 + l15;
            short8 b = *(const short8*)(w2t + (size_t)col * HID_DIM + kb * 32 + q * 8);
            acc[t] = __builtin_amdgcn_mfma_f32_16x16x32_bf16(a, b, acc[t], 0, 0, 0);
        }
    }
#pragma unroll
    for (int t = 0; t < 2; ++t) {
        int col = wv * 32 + t * 16 + l15;
#pragma unroll
        for (int r = 0; r < 4; ++r) {
            int row = row0 + q * 4 + r;
            h2b[(size_t)row * OUT_DIM + col] = f2b(acc[t][r]);
        }
    }
}

// ---------------- gather2: out = Ahat * h2 + b2  (bf16 in, fp32 out) ----------------

__global__ __launch_bounds__(256) void gather2_kernel(const int* __restrict__ cnt,
                                                      const int* __restrict__ bucket,
                                                      const float* __restrict__ dinv,
                                                      const ushort* __restrict__ h2b,
                                                      const float* __restrict__ b2,
                                                      float* __restrict__ out) {
    const int w = blockIdx.x * 4 + (threadIdx.x >> 6);
    const int lane = threadIdx.x & 63;
    const int n = cnt[w];
    const float dd = dinv[w];
    int   sv = (lane < n) ? bucket[w * BUCKET_CAP + lane] : 0;
    float nv = (lane < n) ? dinv[sv] * dd : 0.f;

    float2 bb = ((const float2*)b2)[lane];
    float2 self = u2f2(((const unsigned*)(h2b + (size_t)w * OUT_DIM))[lane]);
    float sd = dd * dd;
    float2 acc0 = {self.x * sd + bb.x, self.y * sd + bb.y};
    float2 acc1 = {0.f, 0.f}, acc2 = {0.f, 0.f}, acc3 = {0.f, 0.f};

    int i = 0;
    for (; i + 3 < n; i += 4) {
        int s0 = __shfl(sv, i), s1 = __shfl(sv, i + 1), s2 = __shfl(sv, i + 2), s3 = __shfl(sv, i + 3);
        float n0 = __shfl(nv, i), n1 = __shfl(nv, i + 1), n2 = __shfl(nv, i + 2), n3 = __shfl(nv, i + 3);
        unsigned u0 = ((const unsigned*)(h2b + (size_t)s0 * OUT_DIM))[lane];
        unsigned u1 = ((const unsigned*)(h2b + (size_t)s1 * OUT_DIM))[lane];
        unsigned u2 = ((const unsigned*)(h2b + (size_t)s2 * OUT_DIM))[lane];
        unsigned u3 = ((const unsigned*)(h2b + (size_t)s3 * OUT_DIM))[lane];
        fma2(acc0, u2f2(u0), n0); fma2(acc1, u2f2(u1), n1);
        fma2(acc2, u2f2(u2), n2); fma2(acc3, u2f2(u3), n3);
    }
    for (; i < n; ++i) {
        int s = __shfl(sv, i);
        float nm = __shfl(nv, i);
        fma2(acc0, u2f2(((const unsigned*)(h2b + (size_t)s * OUT_DIM))[lane]), nm);
    }
    acc0.x += acc1.x + acc2.x + acc3.x;
    acc0.y += acc1.y + acc2.y + acc3.y;
    ((float2*)(out + (size_t)w * OUT_DIM))[lane] = acc0;
}

extern "C" void kernel_launch(void* const* d_in, const int* in_sizes, int n_in,
                              void* d_out, int out_size, void* d_ws, size_t ws_size,
                              hipStream_t stream) {
    const float* x  = (const float*)d_in[0];
    const int*   ei = (const int*)d_in[1];
    const float* W1 = (const float*)d_in[2];
    const float* b1 = (const float*)d_in[3];
    const float* W2 = (const float*)d_in[4];
    const float* b2 = (const float*)d_in[5];
    float* out = (float*)d_out;

    const int* src = ei;             // edge_index[0]
    const int* dst = ei + N_EDGES;   // edge_index[1]

    // workspace layout (bytes):
    //  cnt    : [0, 200000)                 int[50000]
    //  dinv   : [200000, 400000)            float[50000]
    //  bucket : [400000, 13200000)          int[50000*64]
    //  xb     : [13200000, 26000000)        bf16[50000*128]
    //  aggxb  : [26000000, 38800000)        bf16[50000*128]
    //  w1t    : [38800000, 38865536)        bf16[256*128]  (W1 transposed)
    //  w2t    : [38865536, 38931072)        bf16[128*256]  (W2 transposed)
    //  Hb     : [38931072, 64531072)        bf16[50000*256]
    //  h2b    : [64531072, 77331072)        bf16[50000*128]
    char* ws = (char*)d_ws;
    int*    cnt    = (int*)(ws);
    float*  dinv   = (float*)(ws + 200000);
    int*    bucket = (int*)(ws + 400000);
    ushort* xb     = (ushort*)(ws + 13200000);
    ushort* aggxb  = (ushort*)(ws + 26000000);
    ushort* w1t    = (ushort*)(ws + 38800000);
    ushort* w2t    = (ushort*)(ws + 38865536);
    ushort* Hb     = (ushort*)(ws + 38931072);
    ushort* h2b    = (ushort*)(ws + 64531072);

    // graph build + dtype prep
    zero_int_kernel<<<(N_NODES + 255) / 256, 256, 0, stream>>>(cnt, N_NODES);
    fill_bucket_kernel<<<N_EDGES / 256, 256, 0, stream>>>(src, dst, cnt, bucket);
    dinv_kernel<<<(N_NODES + 255) / 256, 256, 0, stream>>>(cnt, dinv);
    conv_x_kernel<<<(N_NODES * IN_DIM / 4) / 256, 256, 0, stream>>>(x, xb);
    conv_w_kernel<<<65536 / 256, 256, 0, stream>>>(W1, W2, w1t, w2t);

    // layer 1 reordered: aggregate x first, then transform (relu+b1 fused in epilogue)
    gather0_kernel<<<N_NODES / 4, 256, 0, stream>>>(cnt, bucket, dinv, xb, aggxb);
    gemm1_mfma<<<N_NODES / 16, 256, 0, stream>>>(aggxb, w1t, b1, Hb);

    // layer 2: transform then aggregate (self-loop + b2 fused into gather2)
    gemm2_mfma<<<N_NODES / 16, 256, 0, stream>>>(Hb, w2t, h2b);
    gather2_kernel<<<N_NODES / 4, 256, 0, stream>>>(cnt, bucket, dinv, h2b, b2, out);
}